// Round 10
// baseline (438.853 us; speedup 1.0000x reference)
//
#include <hip/hip_runtime.h>
#include <math.h>

typedef __attribute__((ext_vector_type(8))) short bf16x8;
typedef __attribute__((ext_vector_type(16))) float f32x16;

#define Bsz 4
#define Nn 1024
#define TN 3072
#define Dd 256
#define Hh 4
#define DH 64
#define TAUc 1e-3f
#define QSCALE 0.1803368801111f   // log2(e)/8 : softmax done in exp2 domain

// workspace layout (float offsets)
#define SALP_OFF 0           // 98304 (4 b x 96 slabs x 256 d partial sums)
#define IDX_OFF  98304       // 256 ints
#define XCB_OFF  98560       // bf16 (4,3072,64) = 393216 floats
#define WCT_OFF  491776      // bf16 (4,3,256,64) = 98304 floats
#define QB_OFF   590080      // bf16 (16,3072,64) linear
#define KB_OFF   2162944     // bf16 (16 bh,24 tiles,128 row,8 chunk,8) swizzled tiles
#define VT_OFF   3735808     // bf16 (16 bh,24 tiles,64 row,16 chunk,8) swizzled tiles
#define OP0_OFF  5308672     // fp32 split-K partials, nspl x 3145728 contiguous
#define OPSTR    3145728     // floats per partial (4,3072,256)
#define SML2_OFF 11600128    // nspl=2: float [2][16][3072] row sums
#define SML4_OFF 17891584    // nspl=4: float [4][16][3072] row sums
#define WS4_NEED ((size_t)(17891584 + 4 * 49152) * 4)   // bytes for nspl=4

__device__ __forceinline__ ushort f2b(float f) {
    uint u = __float_as_uint(f);
    u += 0x7fffu + ((u >> 16) & 1u);
    return (ushort)(u >> 16);
}
__device__ __forceinline__ uint pk2(float a, float b) {   // RNE pack (software)
    return (uint)f2b(a) | ((uint)f2b(b) << 16);
}
__device__ __forceinline__ uint trunc_pk(float a, float b) {
    return (__float_as_uint(a) >> 16) | (__float_as_uint(b) & 0xFFFF0000u);
}
__device__ __forceinline__ float hi_f(float a) {
    return __uint_as_float(__float_as_uint(a) & 0xFFFF0000u);
}
__device__ __forceinline__ uint cvtpk(float a, float b) {  // HW RNE pack
    uint r;
    asm("v_cvt_pk_bf16_f32 %0, %1, %2" : "=v"(r) : "v"(a), "v"(b));
    return r;
}
// raw v_exp_f32 WITHOUT libm's denorm/range-guard expansion, via the compiler
// builtin so TRANS-op hazard NOPs are inserted (r2 lesson: inline-asm
// v_exp_f32 loses the mandatory TRANS->VALU wait state -> stale reads).
__device__ __forceinline__ float ex2(float x) {
    return __builtin_amdgcn_exp2f(x);
}
// async global->LDS DMA, 16B per lane (lane-linear LDS destination)
__device__ __forceinline__ void gld16(const ushort* g, ushort* l) {
    __builtin_amdgcn_global_load_lds(
        (const __attribute__((address_space(1))) uint*)g,
        (__attribute__((address_space(3))) uint*)l, 16, 0, 0);
}
union U4B8 { uint u[4]; bf16x8 v; };
__device__ __forceinline__ bf16x8 ld8(const ushort* p) { return *(const bf16x8*)p; }

// ---- kernel 1: per-channel saliency partial sums ----
__global__ __launch_bounds__(256) void k_sal(
        const float* __restrict__ F0, const float* __restrict__ F1,
        const float* __restrict__ F2, float* __restrict__ salp) {
    int b = blockIdx.x / 96;
    int slab = blockIdx.x - b * 96;
    int t0 = slab * 32;
    int seg = t0 >> 10, tt0 = t0 & 1023;
    const float* F = (seg == 0) ? F0 : (seg == 1 ? F1 : F2);
    const float* base = &F[(size_t)((b << 10) + tt0) * Dd + threadIdx.x];
    float acc = 0.f;
    #pragma unroll 4
    for (int r = 0; r < 32; ++r) {
        float x = base[(size_t)r * Dd];
        acc += fmaxf(fabsf(x) - TAUc, 0.f);
    }
    salp[blockIdx.x * 256 + threadIdx.x] = acc;
}

// ---- kernel 2: reduce partials + top-64 selection (bitonic sort 256) ----
__global__ void k_topk(const float* __restrict__ salp, int* __restrict__ idx) {
    __shared__ float v[256];
    __shared__ int cnt;
    int b = blockIdx.x, tid = threadIdx.x;
    float myval = 0.f;
    const float* p = &salp[(size_t)b * 96 * 256 + tid];
    #pragma unroll 4
    for (int s = 0; s < 96; ++s) myval += p[s * 256];
    v[tid] = myval;
    if (tid == 0) cnt = 0;
    __syncthreads();
    for (int k = 2; k <= 256; k <<= 1)
        for (int j = k >> 1; j > 0; j >>= 1) {
            int ixj = tid ^ j;
            if (ixj > tid) {
                float a = v[tid], c = v[ixj];
                bool up = ((tid & k) == 0);
                if ((a > c) == up) { v[tid] = c; v[ixj] = a; }
            }
            __syncthreads();
        }
    float thr = v[192];
    if (myval >= thr) {
        int p2 = atomicAdd(&cnt, 1);
        if (p2 < 64) idx[b * 64 + p2] = tid;
    }
}

// ---- kernel 3: merged gathers (blocks 0..383: X; 384..767: W columns) ----
__global__ __launch_bounds__(256) void k_gather(
        const float* __restrict__ F0, const float* __restrict__ F1,
        const float* __restrict__ F2,
        const float* __restrict__ Wq, const float* __restrict__ Wk,
        const float* __restrict__ Wv, const int* __restrict__ idx,
        uint* __restrict__ Xcb, uint* __restrict__ Wct) {
    __shared__ float xs[32 * 260];
    __shared__ int ids[64];
    int tid = threadIdx.x;
    if (blockIdx.x < 384) {
        int b = blockIdx.x / 96;
        int t0 = (blockIdx.x - b * 96) * 32;
        if (tid < 64) ids[tid] = idx[b * 64 + tid];
        int seg = t0 >> 10, tt0 = t0 & 1023;
        const float* F = (seg == 0) ? F0 : (seg == 1 ? F1 : F2);
        const float* base = &F[(size_t)((b << 10) + tt0) * Dd];
        #pragma unroll
        for (int i = 0; i < 8; ++i) {
            int i0 = tid + i * 256;
            int r = i0 >> 6, c4 = (i0 & 63) << 2;
            float4 x = *(const float4*)&base[(size_t)r * Dd + c4];
            x.x = copysignf(fmaxf(fabsf(x.x) - TAUc, 0.f), x.x);
            x.y = copysignf(fmaxf(fabsf(x.y) - TAUc, 0.f), x.y);
            x.z = copysignf(fmaxf(fabsf(x.z) - TAUc, 0.f), x.z);
            x.w = copysignf(fmaxf(fabsf(x.w) - TAUc, 0.f), x.w);
            *(float4*)&xs[r * 260 + c4] = x;
        }
        __syncthreads();
        #pragma unroll
        for (int i = 0; i < 4; ++i) {
            int i0 = tid + i * 256;
            int r = i0 >> 5, jp = i0 & 31;
            float x0 = xs[r * 260 + ids[2 * jp]];
            float x1 = xs[r * 260 + ids[2 * jp + 1]];
            Xcb[(size_t)(b * TN + t0 + r) * 32 + jp] = pk2(x0, x1);
        }
    } else {
        int gid = (blockIdx.x - 384) * 256 + tid;   // 98304
        int b = gid / 24576;
        if (tid < 64) ids[tid] = idx[b * 64 + tid];
        __syncthreads();
        int rem = gid - b * 24576;
        int mat = rem / 8192;
        int rem2 = rem - mat * 8192;
        int dout = rem2 >> 5, jp = rem2 & 31;
        const float* Wm = (mat == 0) ? Wq : (mat == 1 ? Wk : Wv);
        float w0 = Wm[(size_t)dout * 256 + ids[2 * jp]];
        float w1 = Wm[(size_t)dout * 256 + ids[2 * jp + 1]];
        Wct[((size_t)(b * 3 + mat) * 256 + dout) * 32 + jp] = pk2(w0, w1);
    }
}

// ---- kernel 4: QKV projection, 32x32x16 MFMA, LDS-free ----
// Q: linear (b,h,t,d), pre-scaled. K/V: written directly in the SWIZZLED TILE
// layout k_attn's LDS image uses, so k_attn can DMA tiles with global_load_lds.
__global__ __launch_bounds__(256) void k_qkv(
        const ushort* __restrict__ Xcb, const ushort* __restrict__ Wct,
        const float* __restrict__ bq, const float* __restrict__ bk,
        const float* __restrict__ bv,
        ushort* __restrict__ Qh, ushort* __restrict__ Kh, ushort* __restrict__ Vt) {
    int wave = threadIdx.x >> 6, lane = threadIdx.x & 63;
    int l31 = lane & 31, h = lane >> 5;
    int W = blockIdx.x * 4 + wave;          // 2304 wave-tasks
    int b = W / 576;
    int r = W - b * 576;
    int mat = r / 192;
    int p = r - mat * 192;
    const ushort* Xb = Xcb + (size_t)b * TN * 64;
    const ushort* Wm = Wct + (size_t)(b * 3 + mat) * 256 * 64;
    f32x16 c[4];
    #pragma unroll
    for (int nt = 0; nt < 4; ++nt)
        #pragma unroll
        for (int q = 0; q < 16; ++q) c[nt][q] = 0.f;
    if (mat < 2) {
        int mtt = p % 96, ng = p / 96;      // t tile, dout half
        const ushort* arow = &Xb[(size_t)(mtt * 32 + l31) * 64];
        #pragma unroll
        for (int kc = 0; kc < 4; ++kc) {
            bf16x8 af = ld8(arow + kc * 16 + 8 * h);
            #pragma unroll
            for (int nt = 0; nt < 4; ++nt) {
                bf16x8 bf = ld8(&Wm[(size_t)(ng * 128 + nt * 32 + l31) * 64 + kc * 16 + 8 * h]);
                c[nt] = __builtin_amdgcn_mfma_f32_32x32x16_bf16(af, bf, c[nt], 0, 0, 0);
            }
        }
        if (mat == 0) {
            // Q: linear coalesced stores, pre-scaled
            #pragma unroll
            for (int nt = 0; nt < 4; ++nt) {
                int dout = ng * 128 + nt * 32 + l31;
                int head = dout >> 6, d63 = dout & 63;
                float bb = bq[dout];
                size_t obase = ((size_t)(b * 4 + head) * TN + mtt * 32) * 64 + d63;
                #pragma unroll
                for (int u = 0; u < 16; ++u) {
                    int trow = (u & 3) + 8 * (u >> 2) + 4 * h;
                    Qh[obase + (size_t)trow * 64] = f2b((c[nt][u] + bb) * QSCALE);
                }
            }
        } else {
            // K: swizzled tile layout: [bh][tile=t>>7][row=t&127][chunk=(d>>3)^fk][d&7]
            #pragma unroll
            for (int nt = 0; nt < 4; ++nt) {
                int dout = ng * 128 + nt * 32 + l31;
                int head = dout >> 6, d63 = dout & 63;
                float bb = bk[dout];
                size_t base = (size_t)(b * 4 + head) * 196608;
                #pragma unroll
                for (int u = 0; u < 16; ++u) {
                    int trow = (u & 3) + 8 * (u >> 2) + 4 * h;
                    int t = mtt * 32 + trow;
                    int row = t & 127, tile = t >> 7;
                    int fk = (row ^ (row >> 3)) & 7;
                    Kh[base + (size_t)tile * 8192 + row * 64 +
                       (((d63 >> 3) ^ fk) << 3) + (d63 & 7)] = f2b(c[nt][u] + bb);
                }
            }
        }
    } else {
        int mtv = p & 7, tg = p >> 3;       // dout tile (8), t group (24 = key tile)
        const ushort* arow = &Wm[(size_t)(mtv * 32 + l31) * 64];
        #pragma unroll
        for (int kc = 0; kc < 4; ++kc) {
            bf16x8 af = ld8(arow + kc * 16 + 8 * h);
            #pragma unroll
            for (int nt = 0; nt < 4; ++nt) {
                bf16x8 bf = ld8(&Xb[(size_t)(tg * 128 + nt * 32 + l31) * 64 + kc * 16 + 8 * h]);
                c[nt] = __builtin_amdgcn_mfma_f32_32x32x16_bf16(af, bf, c[nt], 0, 0, 0);
            }
        }
        int head = mtv >> 1;
        int sl = (l31 & 19) | ((l31 & 4) << 1) | ((l31 & 8) >> 1);  // swap bits 2<->3
        size_t vbase = (size_t)(b * 4 + head) * 196608 + (size_t)tg * 8192;
        // V: swizzled tile: [bh][tile=tg][row=d&63][chunk'=(c&8)|((c&7)^fv)][key&7]
        #pragma unroll
        for (int nt = 0; nt < 4; ++nt) {
            int cc = (nt * 32 + sl) >> 3;   // key chunk within tile (0..15)
            int elem = sl & 7;
            #pragma unroll
            for (int u = 0; u < 16; ++u) {
                int dout = mtv * 32 + (u & 3) + 8 * (u >> 2) + 4 * h;
                int row = dout & 63;
                int fv = (row ^ (row >> 3)) & 7;
                int ch = (cc & 8) | ((cc & 7) ^ fv);
                Vt[vbase + row * 128 + ch * 8 + elem] = f2b(c[nt][u] + bv[dout]);
            }
        }
    }
}

// ---- kernel 5: flash attention. r9 (resubmitted after infra failure):
// de-risked occupancy experiment. Body (stage/compute/double-buffered loop)
// is r7's VERBATIM verified code; only parametrized: nspl-way split-K
// (nhalf = 48/nspl half-tiles per block, base pointers offset by whole
// 128-key tiles, partial index ks). nspl=2 reproduces r7 bit-for-bit.
// launch_bounds(256,5): VGPR cap ~102 >> body's natural 80 (r8's (256,6)
// cap ~84 < ~119 peak live VGPRs forced spills — prime suspect for r8's
// corruption). LDS 32KB x 5 = 160KB exactly.
__global__ __launch_bounds__(256, 5) void k_attn(
        const ushort* __restrict__ Qg, const ushort* __restrict__ Kg,
        const ushort* __restrict__ Vtg,
        float* __restrict__ OPb, float* __restrict__ Sml, int nspl) {
    __shared__ __align__(16) ushort Ks[2][64 * 64];    // [buf][key row][d] swizzled
    __shared__ __align__(16) ushort Vts[2][64 * 64];   // [buf][d row][key] swizzled
    // XCD-aware remap: each XCD serves exactly 2 bh (K/V/Q L2-resident).
    int bid = blockIdx.x;
    int xcd = bid & 7, j0 = bid >> 3;
    int pb = 24 * nspl;                  // blocks per bh within an XCD
    int bhl = j0 / pb;                   // 0 or 1
    int bh = xcd * 2 + bhl;
    int rem = j0 - bhl * pb;
    int qt = rem / nspl;
    int ks = rem - qt * nspl;
    int nhalf = 48 / nspl;               // 64-key half-tiles per split (even)
    int b = bh >> 2, hh = bh & 3;
    int tid = threadIdx.x, wave = tid >> 6, lane = tid & 63;
    int l31 = lane & 31, h = lane >> 5;
    int q0 = qt * 128 + wave * 32;
    const ushort* Qb = Qg + ((size_t)bh * TN + q0 + l31) * DH;
    bf16x8 qf[4];
    #pragma unroll
    for (int kc = 0; kc < 4; ++kc) qf[kc] = ld8(&Qb[kc * 16 + 8 * h]);

    // split base: ks * nhalf half-tiles = whole 128-key tiles (nhalf even)
    const ushort* Ktb = Kg + (size_t)bh * 196608 + (size_t)ks * (nhalf * 4096);
    const ushort* Vtb = Vtg + (size_t)bh * 196608 + (size_t)ks * (nhalf * 4096);

    // per-thread DMA offsets (ushort units). K half-tile: 4096 contiguous.
    // V half-tile: 64 rows x 64 (rows strided 128 in the 128-key source tile).
    int koff0 = tid * 8, koff1 = tid * 8 + 2048;
    int voff0 = (tid >> 3) * 128 + (tid & 7) * 8;
    int voff1 = voff0 + 4096;                       // rows 32..63

    f32x16 o0, o1;
    #pragma unroll
    for (int q = 0; q < 16; ++q) { o0[q] = 0.f; o1[q] = 0.f; }
    f32x16 zf;                 // loop-invariant zero C-operand for QK MFMAs
    #pragma unroll
    for (int q = 0; q < 16; ++q) zf[q] = 0.f;
    float lrun = 0.f;

    int fq0 = (l31 ^ (l31 >> 3)) & 7;
    int fq1 = ((32 + l31) ^ ((32 + l31) >> 3)) & 7;
    int r0c = l31 * 64, r1c = (32 + l31) * 64;

    auto stage = [&](int ht, ushort* KsD, ushort* VtsD) {
        const ushort* ksrc = Ktb + (size_t)ht * 4096;
        const ushort* vsrc = Vtb + (size_t)((ht >> 1) * 8192 + (ht & 1) * 64);
        gld16(ksrc + koff0, KsD + koff0);
        gld16(ksrc + koff1, KsD + koff1);
        gld16(vsrc + voff0, VtsD + koff0);
        gld16(vsrc + voff1, VtsD + koff1);
    };

    auto compute = [&](const ushort* KsB, const ushort* VtsB) {
        f32x16 s0, s1;
        __builtin_amdgcn_s_setprio(1);
        // QK for keys 0-31 (s0) first...
        {
            bf16x8 k0 = ld8(&KsB[r0c + ((h ^ fq0) << 3)]);
            s0 = __builtin_amdgcn_mfma_f32_32x32x16_bf16(k0, qf[0], zf, 0, 0, 0);
        }
        #pragma unroll
        for (int kc = 1; kc < 4; ++kc) {
            bf16x8 k0 = ld8(&KsB[r0c + (((2 * kc + h) ^ fq0) << 3)]);
            s0 = __builtin_amdgcn_mfma_f32_32x32x16_bf16(k0, qf[kc], s0, 0, 0, 0);
        }
        // ...then keys 32-63 (s1): s0's last MFMA drains under these issues.
        {
            bf16x8 k1 = ld8(&KsB[r1c + ((h ^ fq1) << 3)]);
            s1 = __builtin_amdgcn_mfma_f32_32x32x16_bf16(k1, qf[0], zf, 0, 0, 0);
        }
        #pragma unroll
        for (int kc = 1; kc < 4; ++kc) {
            bf16x8 k1 = ld8(&KsB[r1c + (((2 * kc + h) ^ fq1) << 3)]);
            s1 = __builtin_amdgcn_mfma_f32_32x32x16_bf16(k1, qf[kc], s1, 0, 0, 0);
        }
        __builtin_amdgcn_s_setprio(0);
        U4B8 pk4[4];
        float ps0 = 0.f, ps1 = 0.f, ps2 = 0.f, ps3 = 0.f;
        // exp(s0): overlaps s1's MFMA drain
        #pragma unroll
        for (int u = 0; u < 8; ++u) {
            float pa = ex2(s0[2 * u]), pb2 = ex2(s0[2 * u + 1]);
            ps0 += pa; ps1 += pb2;
            pk4[u >> 2].u[u & 3] = cvtpk(pa, pb2);
        }
        // PV chunks 0-1 need only pk4[0..1] (s0-derived): issue them now so
        // the matrix pipe works while exp(s1) runs on the TRANS pipe.
        __builtin_amdgcn_s_setprio(1);
        #pragma unroll
        for (int kc2 = 0; kc2 < 2; ++kc2) {
            int ch = 2 * kc2 + h;
            bf16x8 v0f = ld8(&VtsB[r0c + ((ch ^ fq0) << 3)]);
            bf16x8 v1f = ld8(&VtsB[r1c + ((ch ^ fq1) << 3)]);
            o0 = __builtin_amdgcn_mfma_f32_32x32x16_bf16(pk4[kc2].v, v0f, o0, 0, 0, 0);
            o1 = __builtin_amdgcn_mfma_f32_32x32x16_bf16(pk4[kc2].v, v1f, o1, 0, 0, 0);
        }
        __builtin_amdgcn_s_setprio(0);
        // exp(s1): overlaps PV(0-1) MFMAs
        #pragma unroll
        for (int u = 0; u < 8; ++u) {
            float pa = ex2(s1[2 * u]), pb2 = ex2(s1[2 * u + 1]);
            ps2 += pa; ps3 += pb2;
            pk4[2 + (u >> 2)].u[u & 3] = cvtpk(pa, pb2);
        }
        lrun += (ps0 + ps1) + (ps2 + ps3);
        __builtin_amdgcn_s_setprio(1);
        #pragma unroll
        for (int kc2 = 2; kc2 < 4; ++kc2) {
            int ch = 2 * kc2 + h;
            bf16x8 v0f = ld8(&VtsB[r0c + ((ch ^ fq0) << 3)]);
            bf16x8 v1f = ld8(&VtsB[r1c + ((ch ^ fq1) << 3)]);
            o0 = __builtin_amdgcn_mfma_f32_32x32x16_bf16(pk4[kc2].v, v0f, o0, 0, 0, 0);
            o1 = __builtin_amdgcn_mfma_f32_32x32x16_bf16(pk4[kc2].v, v1f, o1, 0, 0, 0);
        }
        __builtin_amdgcn_s_setprio(0);
    };

    // r7's verified double-buffered loop, trip count nhalf (even).
    stage(0, Ks[0], Vts[0]);
    __syncthreads();
    #pragma unroll 1
    for (int t = 0; t < nhalf; t += 2) {
        stage(t + 1, Ks[1], Vts[1]);        // async: flies under compute(buf0)
        compute(Ks[0], Vts[0]);
        __syncthreads();                    // vmcnt(0): buf1 ready; buf0 free
        if (t + 2 < nhalf) stage(t + 2, Ks[0], Vts[0]);
        compute(Ks[1], Vts[1]);
        __syncthreads();                    // vmcnt(0): buf0 ready; buf1 free
    }

    // one cross-half combine instead of per-tile (sum over tiles commutes)
    lrun += __shfl_xor(lrun, 32);

    float* OP = OPb + (size_t)ks * OPSTR;
    #pragma unroll
    for (int q = 0; q < 16; ++q) {
        int qrow = (q & 3) + 8 * (q >> 2) + 4 * h;
        int t = q0 + qrow;
        size_t base = ((size_t)b * TN + t) * Dd + hh * 64;
        OP[base + l31] = o0[q];
        OP[base + 32 + l31] = o1[q];
    }
    if (h == 0)
        Sml[(size_t)ks * 49152 + (size_t)bh * TN + q0 + l31] = lrun;
}

// ---- kernel 6: output projection — double-buffered LDS, 8 stages x 32 din,
// XOR-swizzled M tile, split-bf16 MFMA, fused combine over nspl partials.
// Grid (192,4): the 4 dout-group blocks sharing OP token rows are 192 apart
// (192 % 8 == 0) -> same XCD -> OP re-reads are L2 hits.
__global__ __launch_bounds__(256) void k_out(
        const float* __restrict__ OPb, const float* __restrict__ Sml,
        const float* __restrict__ Wo, const float* __restrict__ bo,
        float* __restrict__ out, int nspl) {
    __shared__ __align__(16) ushort Ms[2][64][64];   // [buf][t][8 chunks: hi 0-3, lo 4-7]
    __shared__ float invsh[64 * 4];
    int nd4 = blockIdx.y;              // 64-dout group (4)
    int R0 = blockIdx.x * 64;          // 64-token group (192)
    int b = R0 / TN;
    int tloc0 = R0 - b * TN;
    int tid = threadIdx.x, wave = tid >> 6, lane = tid & 63;
    int l31 = lane & 31, h = lane >> 5;
    int wt = wave & 1, wd = wave >> 1;
    {
        int hd = tid >> 6, t = tid & 63;
        size_t o = (size_t)(b * 4 + hd) * TN + tloc0 + t;
        float ssum = 0.f;
        #pragma unroll 2
        for (int sp = 0; sp < nspl; ++sp) ssum += Sml[(size_t)sp * 49152 + o];
        invsh[t * 4 + hd] = 1.f / ssum;
    }
    int dout = nd4 * 64 + wd * 32 + l31;
    float bb = bo[dout];
    const float* wrow = &Wo[(size_t)dout * 256];
    int st_t = tid >> 2, st_c = tid & 3;
    int fst = (st_t ^ (st_t >> 3)) & 7;
    size_t gbase = ((size_t)(b * TN + tloc0 + st_t)) * 256 + st_c * 8;
    int trow = wt * 32 + l31;
    int ftr = (trow ^ (trow >> 3)) & 7;
    f32x16 acc;
    #pragma unroll
    for (int q = 0; q < 16; ++q) acc[q] = 0.f;

    auto stage_load = [&](int st, int buf) {
        size_t ob = gbase + (size_t)st * 32;
        float a0 = 0.f, a1 = 0.f, a2 = 0.f, a3 = 0.f;
        float a4 = 0.f, a5 = 0.f, a6 = 0.f, a7 = 0.f;
        #pragma unroll 2
        for (int sp = 0; sp < nspl; ++sp) {
            const float* P = OPb + (size_t)sp * OPSTR;
            float4 u0 = *(const float4*)&P[ob];
            float4 u1 = *(const float4*)&P[ob + 4];
            a0 += u0.x; a1 += u0.y; a2 += u0.z; a3 += u0.w;
            a4 += u1.x; a5 += u1.y; a6 += u1.z; a7 += u1.w;
        }
        float s = invsh[st_t * 4 + (st >> 1)];
        float m0 = a0 * s, m1 = a1 * s, m2 = a2 * s, m3 = a3 * s;
        float m4 = a4 * s, m5 = a5 * s, m6 = a6 * s, m7 = a7 * s;
        uint4 hi = { trunc_pk(m0, m1), trunc_pk(m2, m3),
                     trunc_pk(m4, m5), trunc_pk(m6, m7) };
        uint4 lo = { trunc_pk(m0 - hi_f(m0), m1 - hi_f(m1)),
                     trunc_pk(m2 - hi_f(m2), m3 - hi_f(m3)),
                     trunc_pk(m4 - hi_f(m4), m5 - hi_f(m5)),
                     trunc_pk(m6 - hi_f(m6), m7 - hi_f(m7)) };
        *(uint4*)&Ms[buf][st_t][(st_c ^ fst) * 8] = hi;
        *(uint4*)&Ms[buf][st_t][((4 + st_c) ^ fst) * 8] = lo;
    };

    __syncthreads();            // invsh visible
    stage_load(0, 0);
    #pragma unroll 1
    for (int st = 0; st < 8; ++st) {
        __syncthreads();        // buf[st&1] visible; previous reads complete
        if (st < 7) stage_load(st + 1, (st + 1) & 1);
        int buf = st & 1;
        #pragma unroll
        for (int kc = 0; kc < 2; ++kc) {
            bf16x8 ah = *(const bf16x8*)&Ms[buf][trow][((2 * kc + h) ^ ftr) * 8];
            bf16x8 al = *(const bf16x8*)&Ms[buf][trow][((4 + 2 * kc + h) ^ ftr) * 8];
            int din0 = st * 32 + kc * 16 + 8 * h;
            float4 w0 = *(const float4*)&wrow[din0];
            float4 w1 = *(const float4*)&wrow[din0 + 4];
            U4B8 wh, wl;
            wh.u[0] = trunc_pk(w0.x, w0.y); wh.u[1] = trunc_pk(w0.z, w0.w);
            wh.u[2] = trunc_pk(w1.x, w1.y); wh.u[3] = trunc_pk(w1.z, w1.w);
            wl.u[0] = trunc_pk(w0.x - hi_f(w0.x), w0.y - hi_f(w0.y));
            wl.u[1] = trunc_pk(w0.z - hi_f(w0.z), w0.w - hi_f(w0.w));
            wl.u[2] = trunc_pk(w1.x - hi_f(w1.x), w1.y - hi_f(w1.y));
            wl.u[3] = trunc_pk(w1.z - hi_f(w1.z), w1.w - hi_f(w1.w));
            acc = __builtin_amdgcn_mfma_f32_32x32x16_bf16(ah, wh.v, acc, 0, 0, 0);
            acc = __builtin_amdgcn_mfma_f32_32x32x16_bf16(al, wh.v, acc, 0, 0, 0);
            acc = __builtin_amdgcn_mfma_f32_32x32x16_bf16(ah, wl.v, acc, 0, 0, 0);
        }
    }
    #pragma unroll
    for (int u = 0; u < 16; ++u) {
        int tloc = tloc0 + wt * 32 + (u & 3) + 8 * (u >> 2) + 4 * h;
        int chunk = tloc >> 10, tt = tloc & 1023;
        out[(size_t)chunk * (Bsz * Nn * Dd) + ((size_t)(b * Nn + tt)) * Dd + dout] =
            acc[u] + bb;
    }
}

extern "C" void kernel_launch(void* const* d_in, const int* in_sizes, int n_in,
                              void* d_out, int out_size, void* d_ws, size_t ws_size,
                              hipStream_t stream) {
    const float* F0 = (const float*)d_in[0];
    const float* F1 = (const float*)d_in[1];
    const float* F2 = (const float*)d_in[2];
    const float* Wq = (const float*)d_in[3];
    const float* bq = (const float*)d_in[4];
    const float* Wk = (const float*)d_in[5];
    const float* bk = (const float*)d_in[6];
    const float* Wv = (const float*)d_in[7];
    const float* bv = (const float*)d_in[8];
    const float* Wo = (const float*)d_in[9];
    const float* bo = (const float*)d_in[10];
    float* ws = (float*)d_ws;
    float* out = (float*)d_out;

    int* idxp = (int*)(ws + IDX_OFF);
    uint* Xcb = (uint*)(ws + XCB_OFF);
    uint* Wct = (uint*)(ws + WCT_OFF);
    ushort* Qb16 = (ushort*)(ws + QB_OFF);
    ushort* Kb16 = (ushort*)(ws + KB_OFF);
    ushort* Vt16 = (ushort*)(ws + VT_OFF);
    float* OP0 = ws + OP0_OFF;

    // 4-way split-K needs 2 extra fp32 partials (+25MB). Guard on ws_size;
    // constant per graph capture. Fallback nspl=2 keeps the verified layout.
    int nspl = (ws_size >= WS4_NEED) ? 4 : 2;
    float* Sml = (nspl == 4) ? (ws + SML4_OFF) : (ws + SML2_OFF);

    k_sal<<<384, 256, 0, stream>>>(F0, F1, F2, ws + SALP_OFF);
    k_topk<<<Bsz, 256, 0, stream>>>(ws + SALP_OFF, idxp);
    k_gather<<<768, 256, 0, stream>>>(F0, F1, F2, Wq, Wk, Wv, idxp, Xcb, Wct);
    k_qkv<<<576, 256, 0, stream>>>((const ushort*)Xcb, (const ushort*)Wct,
                                   bq, bk, bv, Qb16, Kb16, Vt16);
    k_attn<<<384 * nspl, 256, 0, stream>>>(Qb16, Kb16, Vt16, OP0, Sml, nspl);
    k_out<<<dim3(192, 4), 256, 0, stream>>>(OP0, Sml, Wo, bo, out, nspl);
}

// Round 11
// 214.921 us; speedup vs baseline: 2.0419x; 2.0419x over previous
//
#include <hip/hip_runtime.h>
#include <math.h>

typedef __attribute__((ext_vector_type(8))) short bf16x8;
typedef __attribute__((ext_vector_type(16))) float f32x16;

#define Bsz 4
#define Nn 1024
#define TN 3072
#define Dd 256
#define Hh 4
#define DH 64
#define TAUc 1e-3f
#define QSCALE 0.1803368801111f   // log2(e)/8 : softmax done in exp2 domain

// workspace layout (float offsets)
#define SALP_OFF 0           // 98304 (4 b x 96 slabs x 256 d partial sums)
#define IDX_OFF  98304       // 256 ints
#define XCB_OFF  98560       // bf16 (4,3072,64) = 393216 floats
#define WCT_OFF  491776      // bf16 (4,3,256,64) = 98304 floats
#define QB_OFF   590080      // bf16 (16,3072,64) linear
#define KB_OFF   2162944     // bf16 (16 bh,24 tiles,128 row,8 chunk,8) swizzled tiles
#define VT_OFF   3735808     // bf16 (16 bh,24 tiles,64 row,16 chunk,8) swizzled tiles
#define OP0_OFF  5308672     // fp32 split-K partials, nspl x 3145728 contiguous
#define OPSTR    3145728     // floats per partial (4,3072,256)
#define SML2_OFF 11600128    // nspl=2: float [2][16][3072] row sums
#define SML4_OFF 17891584    // nspl=4: float [4][16][3072] row sums
#define WS4_NEED ((size_t)(17891584 + 4 * 49152) * 4)   // bytes for nspl=4

__device__ __forceinline__ ushort f2b(float f) {
    uint u = __float_as_uint(f);
    u += 0x7fffu + ((u >> 16) & 1u);
    return (ushort)(u >> 16);
}
__device__ __forceinline__ uint pk2(float a, float b) {   // RNE pack (software)
    return (uint)f2b(a) | ((uint)f2b(b) << 16);
}
__device__ __forceinline__ uint trunc_pk(float a, float b) {
    return (__float_as_uint(a) >> 16) | (__float_as_uint(b) & 0xFFFF0000u);
}
__device__ __forceinline__ float hi_f(float a) {
    return __uint_as_float(__float_as_uint(a) & 0xFFFF0000u);
}
__device__ __forceinline__ uint cvtpk(float a, float b) {  // HW RNE pack
    uint r;
    asm("v_cvt_pk_bf16_f32 %0, %1, %2" : "=v"(r) : "v"(a), "v"(b));
    return r;
}
// raw v_exp_f32 WITHOUT libm's denorm/range-guard expansion, via the compiler
// builtin so TRANS-op hazard NOPs are inserted (r2 lesson: inline-asm
// v_exp_f32 loses the mandatory TRANS->VALU wait state -> stale reads).
__device__ __forceinline__ float ex2(float x) {
    return __builtin_amdgcn_exp2f(x);
}
// async global->LDS DMA, 16B per lane (lane-linear LDS destination)
__device__ __forceinline__ void gld16(const ushort* g, ushort* l) {
    __builtin_amdgcn_global_load_lds(
        (const __attribute__((address_space(1))) uint*)g,
        (__attribute__((address_space(3))) uint*)l, 16, 0, 0);
}
union U4B8 { uint u[4]; bf16x8 v; };
__device__ __forceinline__ bf16x8 ld8(const ushort* p) { return *(const bf16x8*)p; }

// ---- kernel 1: per-channel saliency partial sums ----
__global__ __launch_bounds__(256) void k_sal(
        const float* __restrict__ F0, const float* __restrict__ F1,
        const float* __restrict__ F2, float* __restrict__ salp) {
    int b = blockIdx.x / 96;
    int slab = blockIdx.x - b * 96;
    int t0 = slab * 32;
    int seg = t0 >> 10, tt0 = t0 & 1023;
    const float* F = (seg == 0) ? F0 : (seg == 1 ? F1 : F2);
    const float* base = &F[(size_t)((b << 10) + tt0) * Dd + threadIdx.x];
    float acc = 0.f;
    #pragma unroll 4
    for (int r = 0; r < 32; ++r) {
        float x = base[(size_t)r * Dd];
        acc += fmaxf(fabsf(x) - TAUc, 0.f);
    }
    salp[blockIdx.x * 256 + threadIdx.x] = acc;
}

// ---- kernel 2: reduce partials + top-64 selection (bitonic sort 256) ----
__global__ void k_topk(const float* __restrict__ salp, int* __restrict__ idx) {
    __shared__ float v[256];
    __shared__ int cnt;
    int b = blockIdx.x, tid = threadIdx.x;
    float myval = 0.f;
    const float* p = &salp[(size_t)b * 96 * 256 + tid];
    #pragma unroll 4
    for (int s = 0; s < 96; ++s) myval += p[s * 256];
    v[tid] = myval;
    if (tid == 0) cnt = 0;
    __syncthreads();
    for (int k = 2; k <= 256; k <<= 1)
        for (int j = k >> 1; j > 0; j >>= 1) {
            int ixj = tid ^ j;
            if (ixj > tid) {
                float a = v[tid], c = v[ixj];
                bool up = ((tid & k) == 0);
                if ((a > c) == up) { v[tid] = c; v[ixj] = a; }
            }
            __syncthreads();
        }
    float thr = v[192];
    if (myval >= thr) {
        int p2 = atomicAdd(&cnt, 1);
        if (p2 < 64) idx[b * 64 + p2] = tid;
    }
}

// ---- kernel 3: merged gathers (blocks 0..383: X; 384..767: W columns) ----
__global__ __launch_bounds__(256) void k_gather(
        const float* __restrict__ F0, const float* __restrict__ F1,
        const float* __restrict__ F2,
        const float* __restrict__ Wq, const float* __restrict__ Wk,
        const float* __restrict__ Wv, const int* __restrict__ idx,
        uint* __restrict__ Xcb, uint* __restrict__ Wct) {
    __shared__ float xs[32 * 260];
    __shared__ int ids[64];
    int tid = threadIdx.x;
    if (blockIdx.x < 384) {
        int b = blockIdx.x / 96;
        int t0 = (blockIdx.x - b * 96) * 32;
        if (tid < 64) ids[tid] = idx[b * 64 + tid];
        int seg = t0 >> 10, tt0 = t0 & 1023;
        const float* F = (seg == 0) ? F0 : (seg == 1 ? F1 : F2);
        const float* base = &F[(size_t)((b << 10) + tt0) * Dd];
        #pragma unroll
        for (int i = 0; i < 8; ++i) {
            int i0 = tid + i * 256;
            int r = i0 >> 6, c4 = (i0 & 63) << 2;
            float4 x = *(const float4*)&base[(size_t)r * Dd + c4];
            x.x = copysignf(fmaxf(fabsf(x.x) - TAUc, 0.f), x.x);
            x.y = copysignf(fmaxf(fabsf(x.y) - TAUc, 0.f), x.y);
            x.z = copysignf(fmaxf(fabsf(x.z) - TAUc, 0.f), x.z);
            x.w = copysignf(fmaxf(fabsf(x.w) - TAUc, 0.f), x.w);
            *(float4*)&xs[r * 260 + c4] = x;
        }
        __syncthreads();
        #pragma unroll
        for (int i = 0; i < 4; ++i) {
            int i0 = tid + i * 256;
            int r = i0 >> 5, jp = i0 & 31;
            float x0 = xs[r * 260 + ids[2 * jp]];
            float x1 = xs[r * 260 + ids[2 * jp + 1]];
            Xcb[(size_t)(b * TN + t0 + r) * 32 + jp] = pk2(x0, x1);
        }
    } else {
        int gid = (blockIdx.x - 384) * 256 + tid;   // 98304
        int b = gid / 24576;
        if (tid < 64) ids[tid] = idx[b * 64 + tid];
        __syncthreads();
        int rem = gid - b * 24576;
        int mat = rem / 8192;
        int rem2 = rem - mat * 8192;
        int dout = rem2 >> 5, jp = rem2 & 31;
        const float* Wm = (mat == 0) ? Wq : (mat == 1 ? Wk : Wv);
        float w0 = Wm[(size_t)dout * 256 + ids[2 * jp]];
        float w1 = Wm[(size_t)dout * 256 + ids[2 * jp + 1]];
        Wct[((size_t)(b * 3 + mat) * 256 + dout) * 32 + jp] = pk2(w0, w1);
    }
}

// ---- kernel 4: QKV projection, 32x32x16 MFMA, LDS-free ----
// Q: linear (b,h,t,d), pre-scaled. K/V: written directly in the SWIZZLED TILE
// layout k_attn's LDS image uses, so k_attn can DMA tiles with global_load_lds.
__global__ __launch_bounds__(256) void k_qkv(
        const ushort* __restrict__ Xcb, const ushort* __restrict__ Wct,
        const float* __restrict__ bq, const float* __restrict__ bk,
        const float* __restrict__ bv,
        ushort* __restrict__ Qh, ushort* __restrict__ Kh, ushort* __restrict__ Vt) {
    int wave = threadIdx.x >> 6, lane = threadIdx.x & 63;
    int l31 = lane & 31, h = lane >> 5;
    int W = blockIdx.x * 4 + wave;          // 2304 wave-tasks
    int b = W / 576;
    int r = W - b * 576;
    int mat = r / 192;
    int p = r - mat * 192;
    const ushort* Xb = Xcb + (size_t)b * TN * 64;
    const ushort* Wm = Wct + (size_t)(b * 3 + mat) * 256 * 64;
    f32x16 c[4];
    #pragma unroll
    for (int nt = 0; nt < 4; ++nt)
        #pragma unroll
        for (int q = 0; q < 16; ++q) c[nt][q] = 0.f;
    if (mat < 2) {
        int mtt = p % 96, ng = p / 96;      // t tile, dout half
        const ushort* arow = &Xb[(size_t)(mtt * 32 + l31) * 64];
        #pragma unroll
        for (int kc = 0; kc < 4; ++kc) {
            bf16x8 af = ld8(arow + kc * 16 + 8 * h);
            #pragma unroll
            for (int nt = 0; nt < 4; ++nt) {
                bf16x8 bf = ld8(&Wm[(size_t)(ng * 128 + nt * 32 + l31) * 64 + kc * 16 + 8 * h]);
                c[nt] = __builtin_amdgcn_mfma_f32_32x32x16_bf16(af, bf, c[nt], 0, 0, 0);
            }
        }
        if (mat == 0) {
            // Q: linear coalesced stores, pre-scaled
            #pragma unroll
            for (int nt = 0; nt < 4; ++nt) {
                int dout = ng * 128 + nt * 32 + l31;
                int head = dout >> 6, d63 = dout & 63;
                float bb = bq[dout];
                size_t obase = ((size_t)(b * 4 + head) * TN + mtt * 32) * 64 + d63;
                #pragma unroll
                for (int u = 0; u < 16; ++u) {
                    int trow = (u & 3) + 8 * (u >> 2) + 4 * h;
                    Qh[obase + (size_t)trow * 64] = f2b((c[nt][u] + bb) * QSCALE);
                }
            }
        } else {
            // K: swizzled tile layout: [bh][tile=t>>7][row=t&127][chunk=(d>>3)^fk][d&7]
            #pragma unroll
            for (int nt = 0; nt < 4; ++nt) {
                int dout = ng * 128 + nt * 32 + l31;
                int head = dout >> 6, d63 = dout & 63;
                float bb = bk[dout];
                size_t base = (size_t)(b * 4 + head) * 196608;
                #pragma unroll
                for (int u = 0; u < 16; ++u) {
                    int trow = (u & 3) + 8 * (u >> 2) + 4 * h;
                    int t = mtt * 32 + trow;
                    int row = t & 127, tile = t >> 7;
                    int fk = (row ^ (row >> 3)) & 7;
                    Kh[base + (size_t)tile * 8192 + row * 64 +
                       (((d63 >> 3) ^ fk) << 3) + (d63 & 7)] = f2b(c[nt][u] + bb);
                }
            }
        }
    } else {
        int mtv = p & 7, tg = p >> 3;       // dout tile (8), t group (24 = key tile)
        const ushort* arow = &Wm[(size_t)(mtv * 32 + l31) * 64];
        #pragma unroll
        for (int kc = 0; kc < 4; ++kc) {
            bf16x8 af = ld8(arow + kc * 16 + 8 * h);
            #pragma unroll
            for (int nt = 0; nt < 4; ++nt) {
                bf16x8 bf = ld8(&Xb[(size_t)(tg * 128 + nt * 32 + l31) * 64 + kc * 16 + 8 * h]);
                c[nt] = __builtin_amdgcn_mfma_f32_32x32x16_bf16(af, bf, c[nt], 0, 0, 0);
            }
        }
        int head = mtv >> 1;
        int sl = (l31 & 19) | ((l31 & 4) << 1) | ((l31 & 8) >> 1);  // swap bits 2<->3
        size_t vbase = (size_t)(b * 4 + head) * 196608 + (size_t)tg * 8192;
        // V: swizzled tile: [bh][tile=tg][row=d&63][chunk'=(c&8)|((c&7)^fv)][key&7]
        #pragma unroll
        for (int nt = 0; nt < 4; ++nt) {
            int cc = (nt * 32 + sl) >> 3;   // key chunk within tile (0..15)
            int elem = sl & 7;
            #pragma unroll
            for (int u = 0; u < 16; ++u) {
                int dout = mtv * 32 + (u & 3) + 8 * (u >> 2) + 4 * h;
                int row = dout & 63;
                int fv = (row ^ (row >> 3)) & 7;
                int ch = (cc & 8) | ((cc & 7) ^ fv);
                Vt[vbase + row * 128 + ch * 8 + elem] = f2b(c[nt][u] + bv[dout]);
            }
        }
    }
}

// ---- kernel 5: flash attention. r11: register-footprint cut for 4 blocks/CU.
// r10 exposed the mechanism: footprint ~144 total regs (80 arch + 64 acc)
// pins occupancy at 3 waves/SIMD; (256,5)'s 102-reg budget caused massive
// spills (VGPR 48, 1.28GB scratch traffic) though nspl=4 logic was CORRECT.
// This round: remove zf (16 live arch regs -> per-tile zero-init, r0/r1
// style, bit-identical), fold fq1=fq0^4 and r1c=r0c+2048 (algebraic
// identities), launch_bounds(256,4) -> budget 128 = 64 arch + 64 acc.
// Body otherwise r7's verified compute; nspl=4 indexing verified by r10.
__global__ __launch_bounds__(256, 4) void k_attn(
        const ushort* __restrict__ Qg, const ushort* __restrict__ Kg,
        const ushort* __restrict__ Vtg,
        float* __restrict__ OPb, float* __restrict__ Sml, int nspl) {
    __shared__ __align__(16) ushort Ks[2][64 * 64];    // [buf][key row][d] swizzled
    __shared__ __align__(16) ushort Vts[2][64 * 64];   // [buf][d row][key] swizzled
    // XCD-aware remap: each XCD serves exactly 2 bh (K/V/Q L2-resident).
    int bid = blockIdx.x;
    int xcd = bid & 7, j0 = bid >> 3;
    int pb = 24 * nspl;                  // blocks per bh within an XCD
    int bhl = j0 / pb;                   // 0 or 1
    int bh = xcd * 2 + bhl;
    int rem = j0 - bhl * pb;
    int qt = rem / nspl;
    int ks = rem - qt * nspl;
    int nhalf = 48 / nspl;               // 64-key half-tiles per split (even)
    int b = bh >> 2, hh = bh & 3;
    int tid = threadIdx.x, wave = tid >> 6, lane = tid & 63;
    int l31 = lane & 31, h = lane >> 5;
    int q0 = qt * 128 + wave * 32;
    const ushort* Qb = Qg + ((size_t)bh * TN + q0 + l31) * DH;
    bf16x8 qf[4];
    #pragma unroll
    for (int kc = 0; kc < 4; ++kc) qf[kc] = ld8(&Qb[kc * 16 + 8 * h]);

    // split base: ks * nhalf half-tiles = whole 128-key tiles (nhalf even)
    const ushort* Ktb = Kg + (size_t)bh * 196608 + (size_t)ks * (nhalf * 4096);
    const ushort* Vtb = Vtg + (size_t)bh * 196608 + (size_t)ks * (nhalf * 4096);

    // per-thread DMA offsets (ushort units). K half-tile: 4096 contiguous.
    // V half-tile: 64 rows x 64 (rows strided 128 in the 128-key source tile).
    int koff0 = tid * 8, koff1 = tid * 8 + 2048;
    int voff0 = (tid >> 3) * 128 + (tid & 7) * 8;
    int voff1 = voff0 + 4096;                       // rows 32..63

    f32x16 o0, o1;
    #pragma unroll
    for (int q = 0; q < 16; ++q) { o0[q] = 0.f; o1[q] = 0.f; }
    float lrun = 0.f;

    int fq0 = (l31 ^ (l31 >> 3)) & 7;
    int fq1 = fq0 ^ 4;                 // ((32+l31)^((32+l31)>>3))&7 == fq0^4
    int r0c = l31 * 64, r1c = r0c + 2048;

    auto stage = [&](int ht, ushort* KsD, ushort* VtsD) {
        const ushort* ksrc = Ktb + (size_t)ht * 4096;
        const ushort* vsrc = Vtb + (size_t)((ht >> 1) * 8192 + (ht & 1) * 64);
        gld16(ksrc + koff0, KsD + koff0);
        gld16(ksrc + koff1, KsD + koff1);
        gld16(vsrc + voff0, VtsD + koff0);
        gld16(vsrc + voff1, VtsD + koff1);
    };

    auto compute = [&](const ushort* KsB, const ushort* VtsB) {
        f32x16 s0, s1;
        // per-tile zero-init (r0/r1 style): no loop-invariant zero vector
        // holding 16 arch regs live across the whole kernel.
        #pragma unroll
        for (int q = 0; q < 16; ++q) { s0[q] = 0.f; s1[q] = 0.f; }
        __builtin_amdgcn_s_setprio(1);
        // QK for keys 0-31 (s0) first...
        #pragma unroll
        for (int kc = 0; kc < 4; ++kc) {
            bf16x8 k0 = ld8(&KsB[r0c + (((2 * kc + h) ^ fq0) << 3)]);
            s0 = __builtin_amdgcn_mfma_f32_32x32x16_bf16(k0, qf[kc], s0, 0, 0, 0);
        }
        // ...then keys 32-63 (s1): s0's last MFMA drains under these issues.
        #pragma unroll
        for (int kc = 0; kc < 4; ++kc) {
            bf16x8 k1 = ld8(&KsB[r1c + (((2 * kc + h) ^ fq1) << 3)]);
            s1 = __builtin_amdgcn_mfma_f32_32x32x16_bf16(k1, qf[kc], s1, 0, 0, 0);
        }
        __builtin_amdgcn_s_setprio(0);
        U4B8 pk4[4];
        float ps0 = 0.f, ps1 = 0.f, ps2 = 0.f, ps3 = 0.f;
        // exp(s0): overlaps s1's MFMA drain
        #pragma unroll
        for (int u = 0; u < 8; ++u) {
            float pa = ex2(s0[2 * u]), pb2 = ex2(s0[2 * u + 1]);
            ps0 += pa; ps1 += pb2;
            pk4[u >> 2].u[u & 3] = cvtpk(pa, pb2);
        }
        // PV chunks 0-1 need only pk4[0..1] (s0-derived): issue them now so
        // the matrix pipe works while exp(s1) runs on the TRANS pipe.
        __builtin_amdgcn_s_setprio(1);
        #pragma unroll
        for (int kc2 = 0; kc2 < 2; ++kc2) {
            int ch = 2 * kc2 + h;
            bf16x8 v0f = ld8(&VtsB[r0c + ((ch ^ fq0) << 3)]);
            bf16x8 v1f = ld8(&VtsB[r1c + ((ch ^ fq1) << 3)]);
            o0 = __builtin_amdgcn_mfma_f32_32x32x16_bf16(pk4[kc2].v, v0f, o0, 0, 0, 0);
            o1 = __builtin_amdgcn_mfma_f32_32x32x16_bf16(pk4[kc2].v, v1f, o1, 0, 0, 0);
        }
        __builtin_amdgcn_s_setprio(0);
        // exp(s1): overlaps PV(0-1) MFMAs
        #pragma unroll
        for (int u = 0; u < 8; ++u) {
            float pa = ex2(s1[2 * u]), pb2 = ex2(s1[2 * u + 1]);
            ps2 += pa; ps3 += pb2;
            pk4[2 + (u >> 2)].u[u & 3] = cvtpk(pa, pb2);
        }
        lrun += (ps0 + ps1) + (ps2 + ps3);
        __builtin_amdgcn_s_setprio(1);
        #pragma unroll
        for (int kc2 = 2; kc2 < 4; ++kc2) {
            int ch = 2 * kc2 + h;
            bf16x8 v0f = ld8(&VtsB[r0c + ((ch ^ fq0) << 3)]);
            bf16x8 v1f = ld8(&VtsB[r1c + ((ch ^ fq1) << 3)]);
            o0 = __builtin_amdgcn_mfma_f32_32x32x16_bf16(pk4[kc2].v, v0f, o0, 0, 0, 0);
            o1 = __builtin_amdgcn_mfma_f32_32x32x16_bf16(pk4[kc2].v, v1f, o1, 0, 0, 0);
        }
        __builtin_amdgcn_s_setprio(0);
    };

    // r7's verified double-buffered loop, trip count nhalf (even).
    stage(0, Ks[0], Vts[0]);
    __syncthreads();
    #pragma unroll 1
    for (int t = 0; t < nhalf; t += 2) {
        stage(t + 1, Ks[1], Vts[1]);        // async: flies under compute(buf0)
        compute(Ks[0], Vts[0]);
        __syncthreads();                    // vmcnt(0): buf1 ready; buf0 free
        if (t + 2 < nhalf) stage(t + 2, Ks[0], Vts[0]);
        compute(Ks[1], Vts[1]);
        __syncthreads();                    // vmcnt(0): buf0 ready; buf1 free
    }

    // one cross-half combine instead of per-tile (sum over tiles commutes)
    lrun += __shfl_xor(lrun, 32);

    float* OP = OPb + (size_t)ks * OPSTR;
    #pragma unroll
    for (int q = 0; q < 16; ++q) {
        int qrow = (q & 3) + 8 * (q >> 2) + 4 * h;
        int t = q0 + qrow;
        size_t base = ((size_t)b * TN + t) * Dd + hh * 64;
        OP[base + l31] = o0[q];
        OP[base + 32 + l31] = o1[q];
    }
    if (h == 0)
        Sml[(size_t)ks * 49152 + (size_t)bh * TN + q0 + l31] = lrun;
}

// ---- kernel 6: output projection — double-buffered LDS, 8 stages x 32 din,
// XOR-swizzled M tile, split-bf16 MFMA, fused combine over nspl partials.
// Grid (192,4): the 4 dout-group blocks sharing OP token rows are 192 apart
// (192 % 8 == 0) -> same XCD -> OP re-reads are L2 hits.
__global__ __launch_bounds__(256) void k_out(
        const float* __restrict__ OPb, const float* __restrict__ Sml,
        const float* __restrict__ Wo, const float* __restrict__ bo,
        float* __restrict__ out, int nspl) {
    __shared__ __align__(16) ushort Ms[2][64][64];   // [buf][t][8 chunks: hi 0-3, lo 4-7]
    __shared__ float invsh[64 * 4];
    int nd4 = blockIdx.y;              // 64-dout group (4)
    int R0 = blockIdx.x * 64;          // 64-token group (192)
    int b = R0 / TN;
    int tloc0 = R0 - b * TN;
    int tid = threadIdx.x, wave = tid >> 6, lane = tid & 63;
    int l31 = lane & 31, h = lane >> 5;
    int wt = wave & 1, wd = wave >> 1;
    {
        int hd = tid >> 6, t = tid & 63;
        size_t o = (size_t)(b * 4 + hd) * TN + tloc0 + t;
        float ssum = 0.f;
        #pragma unroll 2
        for (int sp = 0; sp < nspl; ++sp) ssum += Sml[(size_t)sp * 49152 + o];
        invsh[t * 4 + hd] = 1.f / ssum;
    }
    int dout = nd4 * 64 + wd * 32 + l31;
    float bb = bo[dout];
    const float* wrow = &Wo[(size_t)dout * 256];
    int st_t = tid >> 2, st_c = tid & 3;
    int fst = (st_t ^ (st_t >> 3)) & 7;
    size_t gbase = ((size_t)(b * TN + tloc0 + st_t)) * 256 + st_c * 8;
    int trow = wt * 32 + l31;
    int ftr = (trow ^ (trow >> 3)) & 7;
    f32x16 acc;
    #pragma unroll
    for (int q = 0; q < 16; ++q) acc[q] = 0.f;

    auto stage_load = [&](int st, int buf) {
        size_t ob = gbase + (size_t)st * 32;
        float a0 = 0.f, a1 = 0.f, a2 = 0.f, a3 = 0.f;
        float a4 = 0.f, a5 = 0.f, a6 = 0.f, a7 = 0.f;
        #pragma unroll 2
        for (int sp = 0; sp < nspl; ++sp) {
            const float* P = OPb + (size_t)sp * OPSTR;
            float4 u0 = *(const float4*)&P[ob];
            float4 u1 = *(const float4*)&P[ob + 4];
            a0 += u0.x; a1 += u0.y; a2 += u0.z; a3 += u0.w;
            a4 += u1.x; a5 += u1.y; a6 += u1.z; a7 += u1.w;
        }
        float s = invsh[st_t * 4 + (st >> 1)];
        float m0 = a0 * s, m1 = a1 * s, m2 = a2 * s, m3 = a3 * s;
        float m4 = a4 * s, m5 = a5 * s, m6 = a6 * s, m7 = a7 * s;
        uint4 hi = { trunc_pk(m0, m1), trunc_pk(m2, m3),
                     trunc_pk(m4, m5), trunc_pk(m6, m7) };
        uint4 lo = { trunc_pk(m0 - hi_f(m0), m1 - hi_f(m1)),
                     trunc_pk(m2 - hi_f(m2), m3 - hi_f(m3)),
                     trunc_pk(m4 - hi_f(m4), m5 - hi_f(m5)),
                     trunc_pk(m6 - hi_f(m6), m7 - hi_f(m7)) };
        *(uint4*)&Ms[buf][st_t][(st_c ^ fst) * 8] = hi;
        *(uint4*)&Ms[buf][st_t][((4 + st_c) ^ fst) * 8] = lo;
    };

    __syncthreads();            // invsh visible
    stage_load(0, 0);
    #pragma unroll 1
    for (int st = 0; st < 8; ++st) {
        __syncthreads();        // buf[st&1] visible; previous reads complete
        if (st < 7) stage_load(st + 1, (st + 1) & 1);
        int buf = st & 1;
        #pragma unroll
        for (int kc = 0; kc < 2; ++kc) {
            bf16x8 ah = *(const bf16x8*)&Ms[buf][trow][((2 * kc + h) ^ ftr) * 8];
            bf16x8 al = *(const bf16x8*)&Ms[buf][trow][((4 + 2 * kc + h) ^ ftr) * 8];
            int din0 = st * 32 + kc * 16 + 8 * h;
            float4 w0 = *(const float4*)&wrow[din0];
            float4 w1 = *(const float4*)&wrow[din0 + 4];
            U4B8 wh, wl;
            wh.u[0] = trunc_pk(w0.x, w0.y); wh.u[1] = trunc_pk(w0.z, w0.w);
            wh.u[2] = trunc_pk(w1.x, w1.y); wh.u[3] = trunc_pk(w1.z, w1.w);
            wl.u[0] = trunc_pk(w0.x - hi_f(w0.x), w0.y - hi_f(w0.y));
            wl.u[1] = trunc_pk(w0.z - hi_f(w0.z), w0.w - hi_f(w0.w));
            wl.u[2] = trunc_pk(w1.x - hi_f(w1.x), w1.y - hi_f(w1.y));
            wl.u[3] = trunc_pk(w1.z - hi_f(w1.z), w1.w - hi_f(w1.w));
            acc = __builtin_amdgcn_mfma_f32_32x32x16_bf16(ah, wh.v, acc, 0, 0, 0);
            acc = __builtin_amdgcn_mfma_f32_32x32x16_bf16(al, wh.v, acc, 0, 0, 0);
            acc = __builtin_amdgcn_mfma_f32_32x32x16_bf16(ah, wl.v, acc, 0, 0, 0);
        }
    }
    #pragma unroll
    for (int u = 0; u < 16; ++u) {
        int tloc = tloc0 + wt * 32 + (u & 3) + 8 * (u >> 2) + 4 * h;
        int chunk = tloc >> 10, tt = tloc & 1023;
        out[(size_t)chunk * (Bsz * Nn * Dd) + ((size_t)(b * Nn + tt)) * Dd + dout] =
            acc[u] + bb;
    }
}

extern "C" void kernel_launch(void* const* d_in, const int* in_sizes, int n_in,
                              void* d_out, int out_size, void* d_ws, size_t ws_size,
                              hipStream_t stream) {
    const float* F0 = (const float*)d_in[0];
    const float* F1 = (const float*)d_in[1];
    const float* F2 = (const float*)d_in[2];
    const float* Wq = (const float*)d_in[3];
    const float* bq = (const float*)d_in[4];
    const float* Wk = (const float*)d_in[5];
    const float* bk = (const float*)d_in[6];
    const float* Wv = (const float*)d_in[7];
    const float* bv = (const float*)d_in[8];
    const float* Wo = (const float*)d_in[9];
    const float* bo = (const float*)d_in[10];
    float* ws = (float*)d_ws;
    float* out = (float*)d_out;

    int* idxp = (int*)(ws + IDX_OFF);
    uint* Xcb = (uint*)(ws + XCB_OFF);
    uint* Wct = (uint*)(ws + WCT_OFF);
    ushort* Qb16 = (ushort*)(ws + QB_OFF);
    ushort* Kb16 = (ushort*)(ws + KB_OFF);
    ushort* Vt16 = (ushort*)(ws + VT_OFF);
    float* OP0 = ws + OP0_OFF;

    // 4-way split-K needs 2 extra fp32 partials (+25MB). Guard on ws_size;
    // constant per graph capture. Fallback nspl=2 keeps the verified layout.
    int nspl = (ws_size >= WS4_NEED) ? 4 : 2;
    float* Sml = (nspl == 4) ? (ws + SML4_OFF) : (ws + SML2_OFF);

    k_sal<<<384, 256, 0, stream>>>(F0, F1, F2, ws + SALP_OFF);
    k_topk<<<Bsz, 256, 0, stream>>>(ws + SALP_OFF, idxp);
    k_gather<<<768, 256, 0, stream>>>(F0, F1, F2, Wq, Wk, Wv, idxp, Xcb, Wct);
    k_qkv<<<576, 256, 0, stream>>>((const ushort*)Xcb, (const ushort*)Wct,
                                   bq, bk, bv, Qb16, Kb16, Vt16);
    k_attn<<<384 * nspl, 256, 0, stream>>>(Qb16, Kb16, Vt16, OP0, Sml, nspl);
    k_out<<<dim3(192, 4), 256, 0, stream>>>(OP0, Sml, Wo, bo, out, nspl);
}

// Round 12
// 170.402 us; speedup vs baseline: 2.5754x; 1.2613x over previous
//
#include <hip/hip_runtime.h>
#include <math.h>

typedef __attribute__((ext_vector_type(8))) short bf16x8;
typedef __attribute__((ext_vector_type(16))) float f32x16;

#define Bsz 4
#define Nn 1024
#define TN 3072
#define Dd 256
#define Hh 4
#define DH 64
#define TAUc 1e-3f
#define QSCALE 0.1803368801111f   // log2(e)/8 : softmax done in exp2 domain

// workspace layout (float offsets)
#define SALP_OFF 0           // 98304 (4 b x 96 slabs x 256 d partial sums)
#define IDX_OFF  98304       // 256 ints
#define XCB_OFF  98560       // bf16 (4,3072,64) = 393216 floats
#define WCT_OFF  491776      // bf16 (4,3,256,64) = 98304 floats
#define QB_OFF   590080      // bf16 (16,3072,64) linear
#define KB_OFF   2162944     // bf16 (16 bh,24 tiles,128 row,8 chunk,8) swizzled tiles
#define VT_OFF   3735808     // bf16 (16 bh,24 tiles,64 row,16 chunk,8) swizzled tiles
#define OP0_OFF  5308672     // fp32 (4,3072,256) split-K partial 0
#define OP1_OFF  8454400     // fp32 partial 1
#define SML_OFF  11600128    // float [2][16][3072] row sums l

__device__ __forceinline__ ushort f2b(float f) {
    uint u = __float_as_uint(f);
    u += 0x7fffu + ((u >> 16) & 1u);
    return (ushort)(u >> 16);
}
__device__ __forceinline__ uint pk2(float a, float b) {   // RNE pack (software)
    return (uint)f2b(a) | ((uint)f2b(b) << 16);
}
__device__ __forceinline__ uint trunc_pk(float a, float b) {
    return (__float_as_uint(a) >> 16) | (__float_as_uint(b) & 0xFFFF0000u);
}
__device__ __forceinline__ float hi_f(float a) {
    return __uint_as_float(__float_as_uint(a) & 0xFFFF0000u);
}
__device__ __forceinline__ uint cvtpk(float a, float b) {  // HW RNE pack
    uint r;
    asm("v_cvt_pk_bf16_f32 %0, %1, %2" : "=v"(r) : "v"(a), "v"(b));
    return r;
}
// raw v_exp_f32 WITHOUT libm's denorm/range-guard expansion, via the compiler
// builtin so TRANS-op hazard NOPs are inserted (r2 lesson: inline-asm
// v_exp_f32 loses the mandatory TRANS->VALU wait state -> stale reads).
__device__ __forceinline__ float ex2(float x) {
    return __builtin_amdgcn_exp2f(x);
}
// async global->LDS DMA, 16B per lane (lane-linear LDS destination)
__device__ __forceinline__ void gld16(const ushort* g, ushort* l) {
    __builtin_amdgcn_global_load_lds(
        (const __attribute__((address_space(1))) uint*)g,
        (__attribute__((address_space(3))) uint*)l, 16, 0, 0);
}
union U4B8 { uint u[4]; bf16x8 v; };
__device__ __forceinline__ bf16x8 ld8(const ushort* p) { return *(const bf16x8*)p; }

// ---- kernel 1: per-channel saliency partial sums ----
__global__ __launch_bounds__(256) void k_sal(
        const float* __restrict__ F0, const float* __restrict__ F1,
        const float* __restrict__ F2, float* __restrict__ salp) {
    int b = blockIdx.x / 96;
    int slab = blockIdx.x - b * 96;
    int t0 = slab * 32;
    int seg = t0 >> 10, tt0 = t0 & 1023;
    const float* F = (seg == 0) ? F0 : (seg == 1 ? F1 : F2);
    const float* base = &F[(size_t)((b << 10) + tt0) * Dd + threadIdx.x];
    float acc = 0.f;
    #pragma unroll 4
    for (int r = 0; r < 32; ++r) {
        float x = base[(size_t)r * Dd];
        acc += fmaxf(fabsf(x) - TAUc, 0.f);
    }
    salp[blockIdx.x * 256 + threadIdx.x] = acc;
}

// ---- kernel 2: reduce partials + top-64 selection (bitonic sort 256) ----
__global__ void k_topk(const float* __restrict__ salp, int* __restrict__ idx) {
    __shared__ float v[256];
    __shared__ int cnt;
    int b = blockIdx.x, tid = threadIdx.x;
    float myval = 0.f;
    const float* p = &salp[(size_t)b * 96 * 256 + tid];
    #pragma unroll 4
    for (int s = 0; s < 96; ++s) myval += p[s * 256];
    v[tid] = myval;
    if (tid == 0) cnt = 0;
    __syncthreads();
    for (int k = 2; k <= 256; k <<= 1)
        for (int j = k >> 1; j > 0; j >>= 1) {
            int ixj = tid ^ j;
            if (ixj > tid) {
                float a = v[tid], c = v[ixj];
                bool up = ((tid & k) == 0);
                if ((a > c) == up) { v[tid] = c; v[ixj] = a; }
            }
            __syncthreads();
        }
    float thr = v[192];
    if (myval >= thr) {
        int p2 = atomicAdd(&cnt, 1);
        if (p2 < 64) idx[b * 64 + p2] = tid;
    }
}

// ---- kernel 3: merged gathers (blocks 0..383: X; 384..767: W columns) ----
__global__ __launch_bounds__(256) void k_gather(
        const float* __restrict__ F0, const float* __restrict__ F1,
        const float* __restrict__ F2,
        const float* __restrict__ Wq, const float* __restrict__ Wk,
        const float* __restrict__ Wv, const int* __restrict__ idx,
        uint* __restrict__ Xcb, uint* __restrict__ Wct) {
    __shared__ float xs[32 * 260];
    __shared__ int ids[64];
    int tid = threadIdx.x;
    if (blockIdx.x < 384) {
        int b = blockIdx.x / 96;
        int t0 = (blockIdx.x - b * 96) * 32;
        if (tid < 64) ids[tid] = idx[b * 64 + tid];
        int seg = t0 >> 10, tt0 = t0 & 1023;
        const float* F = (seg == 0) ? F0 : (seg == 1 ? F1 : F2);
        const float* base = &F[(size_t)((b << 10) + tt0) * Dd];
        #pragma unroll
        for (int i = 0; i < 8; ++i) {
            int i0 = tid + i * 256;
            int r = i0 >> 6, c4 = (i0 & 63) << 2;
            float4 x = *(const float4*)&base[(size_t)r * Dd + c4];
            x.x = copysignf(fmaxf(fabsf(x.x) - TAUc, 0.f), x.x);
            x.y = copysignf(fmaxf(fabsf(x.y) - TAUc, 0.f), x.y);
            x.z = copysignf(fmaxf(fabsf(x.z) - TAUc, 0.f), x.z);
            x.w = copysignf(fmaxf(fabsf(x.w) - TAUc, 0.f), x.w);
            *(float4*)&xs[r * 260 + c4] = x;
        }
        __syncthreads();
        #pragma unroll
        for (int i = 0; i < 4; ++i) {
            int i0 = tid + i * 256;
            int r = i0 >> 5, jp = i0 & 31;
            float x0 = xs[r * 260 + ids[2 * jp]];
            float x1 = xs[r * 260 + ids[2 * jp + 1]];
            Xcb[(size_t)(b * TN + t0 + r) * 32 + jp] = pk2(x0, x1);
        }
    } else {
        int gid = (blockIdx.x - 384) * 256 + tid;   // 98304
        int b = gid / 24576;
        if (tid < 64) ids[tid] = idx[b * 64 + tid];
        __syncthreads();
        int rem = gid - b * 24576;
        int mat = rem / 8192;
        int rem2 = rem - mat * 8192;
        int dout = rem2 >> 5, jp = rem2 & 31;
        const float* Wm = (mat == 0) ? Wq : (mat == 1 ? Wk : Wv);
        float w0 = Wm[(size_t)dout * 256 + ids[2 * jp]];
        float w1 = Wm[(size_t)dout * 256 + ids[2 * jp + 1]];
        Wct[((size_t)(b * 3 + mat) * 256 + dout) * 32 + jp] = pk2(w0, w1);
    }
}

// ---- kernel 4: QKV projection, 32x32x16 MFMA, LDS-free ----
// Q: linear (b,h,t,d), pre-scaled. K/V: written directly in the SWIZZLED TILE
// layout k_attn's LDS image uses, so k_attn can DMA tiles with global_load_lds.
__global__ __launch_bounds__(256) void k_qkv(
        const ushort* __restrict__ Xcb, const ushort* __restrict__ Wct,
        const float* __restrict__ bq, const float* __restrict__ bk,
        const float* __restrict__ bv,
        ushort* __restrict__ Qh, ushort* __restrict__ Kh, ushort* __restrict__ Vt) {
    int wave = threadIdx.x >> 6, lane = threadIdx.x & 63;
    int l31 = lane & 31, h = lane >> 5;
    int W = blockIdx.x * 4 + wave;          // 2304 wave-tasks
    int b = W / 576;
    int r = W - b * 576;
    int mat = r / 192;
    int p = r - mat * 192;
    const ushort* Xb = Xcb + (size_t)b * TN * 64;
    const ushort* Wm = Wct + (size_t)(b * 3 + mat) * 256 * 64;
    f32x16 c[4];
    #pragma unroll
    for (int nt = 0; nt < 4; ++nt)
        #pragma unroll
        for (int q = 0; q < 16; ++q) c[nt][q] = 0.f;
    if (mat < 2) {
        int mtt = p % 96, ng = p / 96;      // t tile, dout half
        const ushort* arow = &Xb[(size_t)(mtt * 32 + l31) * 64];
        #pragma unroll
        for (int kc = 0; kc < 4; ++kc) {
            bf16x8 af = ld8(arow + kc * 16 + 8 * h);
            #pragma unroll
            for (int nt = 0; nt < 4; ++nt) {
                bf16x8 bf = ld8(&Wm[(size_t)(ng * 128 + nt * 32 + l31) * 64 + kc * 16 + 8 * h]);
                c[nt] = __builtin_amdgcn_mfma_f32_32x32x16_bf16(af, bf, c[nt], 0, 0, 0);
            }
        }
        if (mat == 0) {
            // Q: linear coalesced stores, pre-scaled
            #pragma unroll
            for (int nt = 0; nt < 4; ++nt) {
                int dout = ng * 128 + nt * 32 + l31;
                int head = dout >> 6, d63 = dout & 63;
                float bb = bq[dout];
                size_t obase = ((size_t)(b * 4 + head) * TN + mtt * 32) * 64 + d63;
                #pragma unroll
                for (int u = 0; u < 16; ++u) {
                    int trow = (u & 3) + 8 * (u >> 2) + 4 * h;
                    Qh[obase + (size_t)trow * 64] = f2b((c[nt][u] + bb) * QSCALE);
                }
            }
        } else {
            // K: swizzled tile layout: [bh][tile=t>>7][row=t&127][chunk=(d>>3)^fk][d&7]
            #pragma unroll
            for (int nt = 0; nt < 4; ++nt) {
                int dout = ng * 128 + nt * 32 + l31;
                int head = dout >> 6, d63 = dout & 63;
                float bb = bk[dout];
                size_t base = (size_t)(b * 4 + head) * 196608;
                #pragma unroll
                for (int u = 0; u < 16; ++u) {
                    int trow = (u & 3) + 8 * (u >> 2) + 4 * h;
                    int t = mtt * 32 + trow;
                    int row = t & 127, tile = t >> 7;
                    int fk = (row ^ (row >> 3)) & 7;
                    Kh[base + (size_t)tile * 8192 + row * 64 +
                       (((d63 >> 3) ^ fk) << 3) + (d63 & 7)] = f2b(c[nt][u] + bb);
                }
            }
        }
    } else {
        int mtv = p & 7, tg = p >> 3;       // dout tile (8), t group (24 = key tile)
        const ushort* arow = &Wm[(size_t)(mtv * 32 + l31) * 64];
        #pragma unroll
        for (int kc = 0; kc < 4; ++kc) {
            bf16x8 af = ld8(arow + kc * 16 + 8 * h);
            #pragma unroll
            for (int nt = 0; nt < 4; ++nt) {
                bf16x8 bf = ld8(&Xb[(size_t)(tg * 128 + nt * 32 + l31) * 64 + kc * 16 + 8 * h]);
                c[nt] = __builtin_amdgcn_mfma_f32_32x32x16_bf16(af, bf, c[nt], 0, 0, 0);
            }
        }
        int head = mtv >> 1;
        int sl = (l31 & 19) | ((l31 & 4) << 1) | ((l31 & 8) >> 1);  // swap bits 2<->3
        size_t vbase = (size_t)(b * 4 + head) * 196608 + (size_t)tg * 8192;
        // V: swizzled tile: [bh][tile=tg][row=d&63][chunk'=(c&8)|((c&7)^fv)][key&7]
        #pragma unroll
        for (int nt = 0; nt < 4; ++nt) {
            int cc = (nt * 32 + sl) >> 3;   // key chunk within tile (0..15)
            int elem = sl & 7;
            #pragma unroll
            for (int u = 0; u < 16; ++u) {
                int dout = mtv * 32 + (u & 3) + 8 * (u >> 2) + 4 * h;
                int row = dout & 63;
                int fv = (row ^ (row >> 3)) & 7;
                int ch = (cc & 8) | ((cc & 7) ^ fv);
                Vt[vbase + row * 128 + ch * 8 + elem] = f2b(c[nt][u] + bv[dout]);
            }
        }
    }
}

// ---- kernel 5: flash attention — FINAL (r7 verbatim, twice-verified at
// 48.3-48.9us, absmax 4.88e-4). 64-key tiles, 2-buffer LDS, 2 barriers/tile,
// XCD-locality remap (FETCH 31->9.3MB), slim softmax (builtin exp2, zero
// C-operand, direct union pack), intra-tile QK(s0)->QK(s1)->exp(s0)->
// PV(0-1)->exp(s1)->PV(2-3) interleave. Measured plateau: MfmaUtil 32%,
// VALU 36%, latency-bound at 3 blocks/CU (natural 144-reg footprint).
// Register-cap occupancy experiments refuted: (256,5)->310us, (256,4)->87us
// (spill traffic dominates); cross-tile pipelines race (r5/r6).
__global__ __launch_bounds__(256, 3) void k_attn(
        const ushort* __restrict__ Qg, const ushort* __restrict__ Kg,
        const ushort* __restrict__ Vtg,
        float* __restrict__ OP0, float* __restrict__ OP1,
        float* __restrict__ Sml) {
    __shared__ __align__(16) ushort Ks[2][64 * 64];    // [buf][key row][d] swizzled
    __shared__ __align__(16) ushort Vts[2][64 * 64];   // [buf][d row][key] swizzled
    // XCD-aware remap: each XCD serves exactly 2 bh (K/V/Q L2-resident).
    int bid = blockIdx.x;
    int xcd = bid & 7, j0 = bid >> 3;           // j0 in 0..95
    int bh = xcd * 2 + (j0 / 48);
    int rem = j0 % 48;
    int qt = rem >> 1, ksplit = rem & 1;
    int b = bh >> 2, hh = bh & 3;
    int tid = threadIdx.x, wave = tid >> 6, lane = tid & 63;
    int l31 = lane & 31, h = lane >> 5;
    int q0 = qt * 128 + wave * 32;
    const ushort* Qb = Qg + ((size_t)bh * TN + q0 + l31) * DH;
    bf16x8 qf[4];
    #pragma unroll
    for (int kc = 0; kc < 4; ++kc) qf[kc] = ld8(&Qb[kc * 16 + 8 * h]);

    const ushort* Ktb = Kg + (size_t)bh * 196608 + (size_t)ksplit * 98304;
    const ushort* Vtb = Vtg + (size_t)bh * 196608 + (size_t)ksplit * 98304;

    // per-thread DMA offsets (ushort units). K half-tile: 4096 contiguous.
    // V half-tile: 64 rows x 64 (rows strided 128 in the 128-key source tile).
    int koff0 = tid * 8, koff1 = tid * 8 + 2048;
    int voff0 = (tid >> 3) * 128 + (tid & 7) * 8;
    int voff1 = voff0 + 4096;                       // rows 32..63

    f32x16 o0, o1;
    #pragma unroll
    for (int q = 0; q < 16; ++q) { o0[q] = 0.f; o1[q] = 0.f; }
    f32x16 zf;                 // loop-invariant zero C-operand for QK MFMAs
    #pragma unroll
    for (int q = 0; q < 16; ++q) zf[q] = 0.f;
    float lrun = 0.f;

    int fq0 = (l31 ^ (l31 >> 3)) & 7;
    int fq1 = ((32 + l31) ^ ((32 + l31) >> 3)) & 7;
    int r0c = l31 * 64, r1c = (32 + l31) * 64;

    auto stage = [&](int ht, ushort* KsD, ushort* VtsD) {
        const ushort* ksrc = Ktb + (size_t)ht * 4096;
        const ushort* vsrc = Vtb + (size_t)((ht >> 1) * 8192 + (ht & 1) * 64);
        gld16(ksrc + koff0, KsD + koff0);
        gld16(ksrc + koff1, KsD + koff1);
        gld16(vsrc + voff0, VtsD + koff0);
        gld16(vsrc + voff1, VtsD + koff1);
    };

    auto compute = [&](const ushort* KsB, const ushort* VtsB) {
        f32x16 s0, s1;
        __builtin_amdgcn_s_setprio(1);
        // QK for keys 0-31 (s0) first...
        {
            bf16x8 k0 = ld8(&KsB[r0c + ((h ^ fq0) << 3)]);
            s0 = __builtin_amdgcn_mfma_f32_32x32x16_bf16(k0, qf[0], zf, 0, 0, 0);
        }
        #pragma unroll
        for (int kc = 1; kc < 4; ++kc) {
            bf16x8 k0 = ld8(&KsB[r0c + (((2 * kc + h) ^ fq0) << 3)]);
            s0 = __builtin_amdgcn_mfma_f32_32x32x16_bf16(k0, qf[kc], s0, 0, 0, 0);
        }
        // ...then keys 32-63 (s1): s0's last MFMA drains under these issues.
        {
            bf16x8 k1 = ld8(&KsB[r1c + ((h ^ fq1) << 3)]);
            s1 = __builtin_amdgcn_mfma_f32_32x32x16_bf16(k1, qf[0], zf, 0, 0, 0);
        }
        #pragma unroll
        for (int kc = 1; kc < 4; ++kc) {
            bf16x8 k1 = ld8(&KsB[r1c + (((2 * kc + h) ^ fq1) << 3)]);
            s1 = __builtin_amdgcn_mfma_f32_32x32x16_bf16(k1, qf[kc], s1, 0, 0, 0);
        }
        __builtin_amdgcn_s_setprio(0);
        U4B8 pk4[4];
        float ps0 = 0.f, ps1 = 0.f, ps2 = 0.f, ps3 = 0.f;
        // exp(s0): overlaps s1's MFMA drain
        #pragma unroll
        for (int u = 0; u < 8; ++u) {
            float pa = ex2(s0[2 * u]), pb = ex2(s0[2 * u + 1]);
            ps0 += pa; ps1 += pb;
            pk4[u >> 2].u[u & 3] = cvtpk(pa, pb);
        }
        // PV chunks 0-1 need only pk4[0..1] (s0-derived): issue them now so
        // the matrix pipe works while exp(s1) runs on the TRANS pipe.
        __builtin_amdgcn_s_setprio(1);
        #pragma unroll
        for (int kc2 = 0; kc2 < 2; ++kc2) {
            int ch = 2 * kc2 + h;
            bf16x8 v0f = ld8(&VtsB[r0c + ((ch ^ fq0) << 3)]);
            bf16x8 v1f = ld8(&VtsB[r1c + ((ch ^ fq1) << 3)]);
            o0 = __builtin_amdgcn_mfma_f32_32x32x16_bf16(pk4[kc2].v, v0f, o0, 0, 0, 0);
            o1 = __builtin_amdgcn_mfma_f32_32x32x16_bf16(pk4[kc2].v, v1f, o1, 0, 0, 0);
        }
        __builtin_amdgcn_s_setprio(0);
        // exp(s1): overlaps PV(0-1) MFMAs
        #pragma unroll
        for (int u = 0; u < 8; ++u) {
            float pa = ex2(s1[2 * u]), pb = ex2(s1[2 * u + 1]);
            ps2 += pa; ps3 += pb;
            pk4[2 + (u >> 2)].u[u & 3] = cvtpk(pa, pb);
        }
        lrun += (ps0 + ps1) + (ps2 + ps3);
        __builtin_amdgcn_s_setprio(1);
        #pragma unroll
        for (int kc2 = 2; kc2 < 4; ++kc2) {
            int ch = 2 * kc2 + h;
            bf16x8 v0f = ld8(&VtsB[r0c + ((ch ^ fq0) << 3)]);
            bf16x8 v1f = ld8(&VtsB[r1c + ((ch ^ fq1) << 3)]);
            o0 = __builtin_amdgcn_mfma_f32_32x32x16_bf16(pk4[kc2].v, v0f, o0, 0, 0, 0);
            o1 = __builtin_amdgcn_mfma_f32_32x32x16_bf16(pk4[kc2].v, v1f, o1, 0, 0, 0);
        }
        __builtin_amdgcn_s_setprio(0);
    };

    // prologue: fill buffer 0; __syncthreads drains vmcnt(0) + makes it visible
    stage(0, Ks[0], Vts[0]);
    __syncthreads();
    #pragma unroll 1
    for (int t = 0; t < 24; t += 2) {
        stage(t + 1, Ks[1], Vts[1]);        // async: flies under compute(buf0)
        compute(Ks[0], Vts[0]);
        __syncthreads();                    // vmcnt(0): buf1 ready; buf0 free
        if (t + 2 < 24) stage(t + 2, Ks[0], Vts[0]);
        compute(Ks[1], Vts[1]);
        __syncthreads();                    // vmcnt(0): buf0 ready; buf1 free
    }

    // one cross-half combine instead of per-tile (sum over tiles commutes)
    lrun += __shfl_xor(lrun, 32);

    float* OP = ksplit ? OP1 : OP0;
    #pragma unroll
    for (int q = 0; q < 16; ++q) {
        int qrow = (q & 3) + 8 * (q >> 2) + 4 * h;
        int t = q0 + qrow;
        size_t base = ((size_t)b * TN + t) * Dd + hh * 64;
        OP[base + l31] = o0[q];
        OP[base + 32 + l31] = o1[q];
    }
    if (h == 0)
        Sml[(size_t)ksplit * 49152 + (size_t)bh * TN + q0 + l31] = lrun;
}

// ---- kernel 6: output projection v2 — double-buffered LDS, 8 stages x 32 din,
// XOR-swizzled M tile, split-bf16 MFMA, fused combine. Grid (192,4): the 4
// dout-group blocks sharing the same OP token rows are 192 apart
// (192 % 8 == 0) -> same XCD -> OP re-reads are L2 hits.
__global__ __launch_bounds__(256) void k_out(
        const float* __restrict__ OP0, const float* __restrict__ OP1,
        const float* __restrict__ Sml, const float* __restrict__ Wo,
        const float* __restrict__ bo, float* __restrict__ out) {
    __shared__ __align__(16) ushort Ms[2][64][64];   // [buf][t][8 chunks: hi 0-3, lo 4-7]
    __shared__ float invsh[64 * 4];
    int nd4 = blockIdx.y;              // 64-dout group (4)
    int R0 = blockIdx.x * 64;          // 64-token group (192)
    int b = R0 / TN;
    int tloc0 = R0 - b * TN;
    int tid = threadIdx.x, wave = tid >> 6, lane = tid & 63;
    int l31 = lane & 31, h = lane >> 5;
    int wt = wave & 1, wd = wave >> 1;
    {
        int hd = tid >> 6, t = tid & 63;
        size_t o = (size_t)(b * 4 + hd) * TN + tloc0 + t;
        invsh[t * 4 + hd] = 1.f / (Sml[o] + Sml[49152 + o]);
    }
    int dout = nd4 * 64 + wd * 32 + l31;
    float bb = bo[dout];
    const float* wrow = &Wo[(size_t)dout * 256];
    int st_t = tid >> 2, st_c = tid & 3;
    int fst = (st_t ^ (st_t >> 3)) & 7;
    size_t gbase = ((size_t)(b * TN + tloc0 + st_t)) * 256 + st_c * 8;
    int trow = wt * 32 + l31;
    int ftr = (trow ^ (trow >> 3)) & 7;
    f32x16 acc;
    #pragma unroll
    for (int q = 0; q < 16; ++q) acc[q] = 0.f;

    auto stage_load = [&](int st, int buf) {
        size_t ob = gbase + (size_t)st * 32;
        float4 x0 = *(const float4*)&OP0[ob];
        float4 x1 = *(const float4*)&OP0[ob + 4];
        float4 y0 = *(const float4*)&OP1[ob];
        float4 y1 = *(const float4*)&OP1[ob + 4];
        float s = invsh[st_t * 4 + (st >> 1)];
        float m0 = (x0.x + y0.x) * s, m1 = (x0.y + y0.y) * s;
        float m2 = (x0.z + y0.z) * s, m3 = (x0.w + y0.w) * s;
        float m4 = (x1.x + y1.x) * s, m5 = (x1.y + y1.y) * s;
        float m6 = (x1.z + y1.z) * s, m7 = (x1.w + y1.w) * s;
        uint4 hi = { trunc_pk(m0, m1), trunc_pk(m2, m3),
                     trunc_pk(m4, m5), trunc_pk(m6, m7) };
        uint4 lo = { trunc_pk(m0 - hi_f(m0), m1 - hi_f(m1)),
                     trunc_pk(m2 - hi_f(m2), m3 - hi_f(m3)),
                     trunc_pk(m4 - hi_f(m4), m5 - hi_f(m5)),
                     trunc_pk(m6 - hi_f(m6), m7 - hi_f(m7)) };
        *(uint4*)&Ms[buf][st_t][(st_c ^ fst) * 8] = hi;
        *(uint4*)&Ms[buf][st_t][((4 + st_c) ^ fst) * 8] = lo;
    };

    __syncthreads();            // invsh visible
    stage_load(0, 0);
    #pragma unroll 1
    for (int st = 0; st < 8; ++st) {
        __syncthreads();        // buf[st&1] visible; previous reads complete
        if (st < 7) stage_load(st + 1, (st + 1) & 1);
        int buf = st & 1;
        #pragma unroll
        for (int kc = 0; kc < 2; ++kc) {
            bf16x8 ah = *(const bf16x8*)&Ms[buf][trow][((2 * kc + h) ^ ftr) * 8];
            bf16x8 al = *(const bf16x8*)&Ms[buf][trow][((4 + 2 * kc + h) ^ ftr) * 8];
            int din0 = st * 32 + kc * 16 + 8 * h;
            float4 w0 = *(const float4*)&wrow[din0];
            float4 w1 = *(const float4*)&wrow[din0 + 4];
            U4B8 wh, wl;
            wh.u[0] = trunc_pk(w0.x, w0.y); wh.u[1] = trunc_pk(w0.z, w0.w);
            wh.u[2] = trunc_pk(w1.x, w1.y); wh.u[3] = trunc_pk(w1.z, w1.w);
            wl.u[0] = trunc_pk(w0.x - hi_f(w0.x), w0.y - hi_f(w0.y));
            wl.u[1] = trunc_pk(w0.z - hi_f(w0.z), w0.w - hi_f(w0.w));
            wl.u[2] = trunc_pk(w1.x - hi_f(w1.x), w1.y - hi_f(w1.y));
            wl.u[3] = trunc_pk(w1.z - hi_f(w1.z), w1.w - hi_f(w1.w));
            acc = __builtin_amdgcn_mfma_f32_32x32x16_bf16(ah, wh.v, acc, 0, 0, 0);
            acc = __builtin_amdgcn_mfma_f32_32x32x16_bf16(al, wh.v, acc, 0, 0, 0);
            acc = __builtin_amdgcn_mfma_f32_32x32x16_bf16(ah, wl.v, acc, 0, 0, 0);
        }
    }
    #pragma unroll
    for (int u = 0; u < 16; ++u) {
        int tloc = tloc0 + wt * 32 + (u & 3) + 8 * (u >> 2) + 4 * h;
        int chunk = tloc >> 10, tt = tloc & 1023;
        out[(size_t)chunk * (Bsz * Nn * Dd) + ((size_t)(b * Nn + tt)) * Dd + dout] =
            acc[u] + bb;
    }
}

extern "C" void kernel_launch(void* const* d_in, const int* in_sizes, int n_in,
                              void* d_out, int out_size, void* d_ws, size_t ws_size,
                              hipStream_t stream) {
    const float* F0 = (const float*)d_in[0];
    const float* F1 = (const float*)d_in[1];
    const float* F2 = (const float*)d_in[2];
    const float* Wq = (const float*)d_in[3];
    const float* bq = (const float*)d_in[4];
    const float* Wk = (const float*)d_in[5];
    const float* bk = (const float*)d_in[6];
    const float* Wv = (const float*)d_in[7];
    const float* bv = (const float*)d_in[8];
    const float* Wo = (const float*)d_in[9];
    const float* bo = (const float*)d_in[10];
    float* ws = (float*)d_ws;
    float* out = (float*)d_out;

    int* idxp = (int*)(ws + IDX_OFF);
    uint* Xcb = (uint*)(ws + XCB_OFF);
    uint* Wct = (uint*)(ws + WCT_OFF);
    ushort* Qb16 = (ushort*)(ws + QB_OFF);
    ushort* Kb16 = (ushort*)(ws + KB_OFF);
    ushort* Vt16 = (ushort*)(ws + VT_OFF);
    float* OP0 = ws + OP0_OFF;
    float* OP1 = ws + OP1_OFF;
    float* Sml = ws + SML_OFF;

    k_sal<<<384, 256, 0, stream>>>(F0, F1, F2, ws + SALP_OFF);
    k_topk<<<Bsz, 256, 0, stream>>>(ws + SALP_OFF, idxp);
    k_gather<<<768, 256, 0, stream>>>(F0, F1, F2, Wq, Wk, Wv, idxp, Xcb, Wct);
    k_qkv<<<576, 256, 0, stream>>>((const ushort*)Xcb, (const ushort*)Wct,
                                   bq, bk, bv, Qb16, Kb16, Vt16);
    k_attn<<<768, 256, 0, stream>>>(Qb16, Kb16, Vt16, OP0, OP1, Sml);
    k_out<<<dim3(192, 4), 256, 0, stream>>>(OP0, OP1, Sml, Wo, bo, out);
}